// Round 8
// baseline (159.729 us; speedup 1.0000x reference)
//
#include <hip/hip_runtime.h>
#include <hip/hip_bf16.h>
#include <stdint.h>

#define T_ 4
#define B_ 16
#define C_ 256
#define N_ 1024
#define HEADS_ 8
#define HD_ 32
#define ZOFF 196608   // zero row offset in wqkv (row 256)

typedef unsigned long long u64;
typedef unsigned char u8;
typedef unsigned short u16;

// ---------- prep: wqkv[257][768] (row 256 = zeros), wtp[c][256], BN ----------
__global__ __launch_bounds__(256) void prep_kernel(
    const float* __restrict__ qw, const float* __restrict__ kw,
    const float* __restrict__ vw, const float* __restrict__ pw,
    const float* __restrict__ qg, const float* __restrict__ qb2,
    const float* __restrict__ qmn, const float* __restrict__ qvr,
    const float* __restrict__ kg, const float* __restrict__ kb2,
    const float* __restrict__ kmn, const float* __restrict__ kvr,
    const float* __restrict__ vg, const float* __restrict__ vb2,
    const float* __restrict__ vmn, const float* __restrict__ vvr,
    const float* __restrict__ pg, const float* __restrict__ pb2,
    const float* __restrict__ pmn, const float* __restrict__ pvr,
    float* __restrict__ wqkv, float* __restrict__ wtp,
    float* __restrict__ bnt) {
  if (blockIdx.x < 256) {
    int c = blockIdx.x;
    int o = threadIdx.x;
    wqkv[c * 768 + o]       = qw[o * C_ + c];
    wqkv[c * 768 + 256 + o] = kw[o * C_ + c];
    wqkv[c * 768 + 512 + o] = vw[o * C_ + c];
    wtp[c * C_ + o]         = pw[o * C_ + c];
  } else if (blockIdx.x == 256) {
    int c = threadIdx.x;
    float rs;
    rs = sqrtf(qvr[c] + 1e-5f);
    bnt[0 * C_ + c] = qg[c] / rs;
    bnt[1 * C_ + c] = qb2[c] - qmn[c] * qg[c] / rs;
    rs = sqrtf(kvr[c] + 1e-5f);
    bnt[2 * C_ + c] = kg[c] / rs;
    bnt[3 * C_ + c] = kb2[c] - kmn[c] * kg[c] / rs;
    rs = sqrtf(vvr[c] + 1e-5f);
    bnt[4 * C_ + c] = vg[c] / rs;
    bnt[5 * C_ + c] = vb2[c] - vmn[c] * vg[c] / rs;
    rs = sqrtf(pvr[c] + 1e-5f);
    bnt[6 * C_ + c] = pg[c] / rs;
    bnt[7 * C_ + c] = pb2[c] - pmn[c] * pg[c] / rs;
  } else {
    int o = threadIdx.x;           // zero row
    wqkv[ZOFF + o]       = 0.f;
    wqkv[ZOFF + 256 + o] = 0.f;
    wqkv[ZOFF + 512 + o] = 0.f;
  }
}

// ---------- P0: shortcut LIF -> xsm masks + compact channel lists ----------
__global__ __launch_bounds__(256) void lif_pack(const float* __restrict__ x,
                                                u64* __restrict__ xsm,
                                                u8* __restrict__ lists,
                                                u16* __restrict__ cnts) {
  int b = blockIdx.x >> 5;          // 32 n-tiles of 32
  int n0 = (blockIdx.x & 31) << 5;
  int tid = threadIdx.x;
  int l = tid & 63, w = tid >> 6;
  __shared__ float tile[C_ * 33];
  __shared__ u64 lmask[4][32][4];
  __shared__ u8 slist[128][32];
  float v[32];
#pragma unroll
  for (int i = 0; i < 32; i++) v[i] = 0.f;
  int c = (w << 6) + l;
  for (int t = 0; t < T_; t++) {
    __syncthreads();
    const float* xp = x + (((size_t)t * B_ + b) * C_) * N_ + n0;
    for (int idx = tid; idx < C_ * 32; idx += 256) {
      int cc = idx >> 5, nn = idx & 31;
      tile[cc * 33 + nn] = xp[(size_t)cc * N_ + nn];
    }
    __syncthreads();
#pragma unroll
    for (int nn = 0; nn < 32; nn++) {
      float xv = tile[c * 33 + nn];
      float h = v[nn] + (xv - v[nn]) * 0.5f;
      bool s = h >= 1.0f;
      v[nn] = s ? 0.f : h;
      u64 bal = __ballot(s);
      if (l == nn) {
        lmask[t][nn][w] = bal;
        xsm[(((size_t)t * B_ + b) * N_ + n0 + nn) * 4 + w] = bal;
      }
    }
  }
  __syncthreads();
  // pack: 128 sites (4t x 32nn), ascending channel order
  if (tid < 128) {
    int t = tid >> 5, nn = tid & 31;
    size_t site = ((size_t)t * B_ + b) * N_ + n0 + nn;
    int cnt = 0;
#pragma unroll
    for (int wd = 0; wd < 4; wd++) {
      u64 m = lmask[t][nn][wd];
      while (m) {
        int cc = (wd << 6) + __builtin_ctzll(m);
        m &= m - 1;
        if (cnt < 32) slist[tid][cnt] = (u8)cc;
        cnt++;
      }
    }
    cnts[site] = (u16)cnt;
  }
  __syncthreads();
  // coalesced copy slist -> lists
  {
    int si = tid >> 1, h = tid & 1;
    int t = si >> 5, nn = si & 31;
    size_t site = ((size_t)t * B_ + b) * N_ + n0 + nn;
    ((uint4*)(lists + (site << 5)))[h] = ((uint4*)slist[si])[h];
  }
}

// ---------- P1: sparse q/k/v conv + BN + LIF (unrolled list gather) ----------
// grid = b(16) x nt(64 tiles of 16 n); wave wv owns sites nn = wv+4s.
// lane l owns out-channels o = 4l+j; ballot word j, bit l <-> c = 4l+j.
__global__ __launch_bounds__(256) void qkv_sparse(
    const u64* __restrict__ xsm, const u8* __restrict__ lists,
    const u16* __restrict__ cnts, const float* __restrict__ wqkv,
    const float* __restrict__ bnt, u8* __restrict__ pkvb,
    u64* __restrict__ qm_out, float* __restrict__ vout) {
  int b = blockIdx.x >> 6;
  int nt = blockIdx.x & 63;
  int n0 = nt << 4;
  int tid = threadIdx.x;
  int l = tid & 63, wv = tid >> 6;

  __shared__ u64 kvw[16][4][4];
  __shared__ u64 vb[16][4][4];

  float qsc[4], qsh[4], ksc[4], ksh[4], vsc[4], vsh[4];
#pragma unroll
  for (int j = 0; j < 4; j++) {
    int o = (l << 2) + j;
    qsc[j] = bnt[0 * C_ + o]; qsh[j] = bnt[1 * C_ + o];
    ksc[j] = bnt[2 * C_ + o]; ksh[j] = bnt[3 * C_ + o];
    vsc[j] = bnt[4 * C_ + o]; vsh[j] = bnt[5 * C_ + o];
  }

  for (int s = 0; s < 4; s++) {
    int nn = wv + (s << 2);        // 0..15
    int n = n0 + nn;
    float vq[4] = {0.f, 0.f, 0.f, 0.f};
    float vk[4] = {0.f, 0.f, 0.f, 0.f};
    float vv2[4] = {0.f, 0.f, 0.f, 0.f};
#pragma unroll
    for (int t = 0; t < 4; t++) {
      size_t site = ((size_t)t * B_ + b) * N_ + n;
      int cn = cnts[site];
      float aq[4] = {0.f, 0.f, 0.f, 0.f};
      float ak[4] = {0.f, 0.f, 0.f, 0.f};
      float av[4] = {0.f, 0.f, 0.f, 0.f};
      if (cn > 0 && cn <= 32) {
        const uint4* lp = (const uint4*)(lists + (site << 5));
        uint4 L0 = lp[0], L1 = lp[1];
        unsigned dw[8] = {L0.x, L0.y, L0.z, L0.w, L1.x, L1.y, L1.z, L1.w};
#pragma unroll
        for (int d = 0; d < 8; d++) {
          if ((d << 2) < cn) {
            unsigned w4 = dw[d];
            int i0 = d << 2;
            int c0 = w4 & 255, c1 = (w4 >> 8) & 255;
            int c2 = (w4 >> 16) & 255, c3 = w4 >> 24;
            const float4* p0 =
                (const float4*)(wqkv + (i0 + 0 < cn ? c0 * 768 : ZOFF)) + l;
            const float4* p1 =
                (const float4*)(wqkv + (i0 + 1 < cn ? c1 * 768 : ZOFF)) + l;
            const float4* p2 =
                (const float4*)(wqkv + (i0 + 2 < cn ? c2 * 768 : ZOFF)) + l;
            const float4* p3 =
                (const float4*)(wqkv + (i0 + 3 < cn ? c3 * 768 : ZOFF)) + l;
            float4 q0 = p0[0], k0 = p0[64], v0 = p0[128];
            float4 q1 = p1[0], k1 = p1[64], v1 = p1[128];
            float4 q2 = p2[0], k2 = p2[64], v2 = p2[128];
            float4 q3 = p3[0], k3 = p3[64], v3 = p3[128];
            aq[0] += q0.x; aq[1] += q0.y; aq[2] += q0.z; aq[3] += q0.w;
            ak[0] += k0.x; ak[1] += k0.y; ak[2] += k0.z; ak[3] += k0.w;
            av[0] += v0.x; av[1] += v0.y; av[2] += v0.z; av[3] += v0.w;
            aq[0] += q1.x; aq[1] += q1.y; aq[2] += q1.z; aq[3] += q1.w;
            ak[0] += k1.x; ak[1] += k1.y; ak[2] += k1.z; ak[3] += k1.w;
            av[0] += v1.x; av[1] += v1.y; av[2] += v1.z; av[3] += v1.w;
            aq[0] += q2.x; aq[1] += q2.y; aq[2] += q2.z; aq[3] += q2.w;
            ak[0] += k2.x; ak[1] += k2.y; ak[2] += k2.z; ak[3] += k2.w;
            av[0] += v2.x; av[1] += v2.y; av[2] += v2.z; av[3] += v2.w;
            aq[0] += q3.x; aq[1] += q3.y; aq[2] += q3.z; aq[3] += q3.w;
            ak[0] += k3.x; ak[1] += k3.y; ak[2] += k3.z; ak[3] += k3.w;
            av[0] += v3.x; av[1] += v3.y; av[2] += v3.z; av[3] += v3.w;
          }
        }
      } else if (cn > 32) {
        // overflow fallback: direct mask walk (never expected in practice)
        const u64* mp = xsm + (site << 2);
#pragma unroll
        for (int wd = 0; wd < 4; wd++) {
          u64 m = mp[wd];
          while (m) {
            int cc = (wd << 6) + __builtin_ctzll(m);
            m &= m - 1;
            const float4* pb = (const float4*)(wqkv + cc * 768) + l;
            float4 q0 = pb[0], k0 = pb[64], v0 = pb[128];
            aq[0] += q0.x; aq[1] += q0.y; aq[2] += q0.z; aq[3] += q0.w;
            ak[0] += k0.x; ak[1] += k0.y; ak[2] += k0.z; ak[3] += k0.w;
            av[0] += v0.x; av[1] += v0.y; av[2] += v0.z; av[3] += v0.w;
          }
        }
      }
      // BN + LIF step for this t
#pragma unroll
      for (int j = 0; j < 4; j++) {
        float pq = aq[j] * qsc[j] + qsh[j];
        float pk = ak[j] * ksc[j] + ksh[j];
        float pv = av[j] * vsc[j] + vsh[j];
        float hq = vq[j] + (pq - vq[j]) * 0.5f;
        float hk = vk[j] + (pk - vk[j]) * 0.5f;
        float hv = vv2[j] + (pv - vv2[j]) * 0.5f;
        bool sq = hq >= 1.0f; vq[j] = sq ? 0.f : hq;
        bool sk = hk >= 1.0f; vk[j] = sk ? 0.f : hk;
        bool sv = hv >= 1.0f; vv2[j] = sv ? 0.f : hv;
        u64 bq = __ballot(sq);
        u64 bkv = __ballot(sk && sv);
        u64 bv = __ballot(sv);
        if (l == (t << 2) + j) {
          qm_out[(site << 2) + j] = bq;
          kvw[nn][t][j] = bkv;
          vb[nn][t][j] = bv;
        }
      }
    }
  }
  __syncthreads();

  // pkv partial-count write: per (t,c), count over the block's 16 sites
#pragma unroll
  for (int t = 0; t < 4; t++) {
    int c = tid;
    int ll = c >> 2, j = c & 3;
    int ssum = 0;
#pragma unroll
    for (int s16 = 0; s16 < 16; s16++)
      ssum += (int)((kvw[s16][t][j] >> ll) & 1ull);
    pkvb[((((size_t)t * B_ + b) * C_ + c) << 6) + nt] = (u8)ssum;
  }

  // coalesced vout write: 32 (t,head) groups x 8 threads; 2 sites each
  {
    int th = tid >> 3;
    int t = th >> 3;
    int head = th & 7;
    int nl0 = tid & 7;
#pragma unroll
    for (int rep = 0; rep < 2; rep++) {
      int nl = nl0 + (rep << 3);
      float* vp = vout +
          ((((size_t)t * B_ + b) * HEADS_ + head) * N_ + n0 + nl) * HD_;
#pragma unroll
      for (int m4 = 0; m4 < 8; m4++) {
        int li = (head << 3) + m4;
        float4 o4;
        o4.x = ((vb[nl][t][0] >> li) & 1ull) ? 1.f : 0.f;
        o4.y = ((vb[nl][t][1] >> li) & 1ull) ? 1.f : 0.f;
        o4.z = ((vb[nl][t][2] >> li) & 1ull) ? 1.f : 0.f;
        o4.w = ((vb[nl][t][3] >> li) & 1ull) ? 1.f : 0.f;
        *(float4*)(vp + (m4 << 2)) = o4;
      }
    }
  }
}

// ---------- P2: reduce kv partials + talking-heads LIF (v_th=0.5) ----------
__global__ __launch_bounds__(256) void kv_lif_kernel(const u8* __restrict__ pkvb,
                                                     u64* __restrict__ kvsm) {
  int b = blockIdx.x;
  int tid = threadIdx.x;
  int l = tid & 63, j = tid >> 6;
  int c = (l << 2) + j;
  float v = 0.f;
  for (int t = 0; t < 4; t++) {
    const uint4* p =
        (const uint4*)(pkvb + ((((size_t)t * B_ + b) * C_ + c) << 6));
    int s = 0;
#pragma unroll
    for (int i = 0; i < 4; i++) {
      uint4 u = p[i];
      unsigned a;
      a = u.x; s += (a & 255) + ((a >> 8) & 255) + ((a >> 16) & 255) + (a >> 24);
      a = u.y; s += (a & 255) + ((a >> 8) & 255) + ((a >> 16) & 255) + (a >> 24);
      a = u.z; s += (a & 255) + ((a >> 8) & 255) + ((a >> 16) & 255) + (a >> 24);
      a = u.w; s += (a & 255) + ((a >> 8) & 255) + ((a >> 16) & 255) + (a >> 24);
    }
    float kvs = (float)s;
    float h = v + (kvs - v) * 0.5f;
    bool sp = h >= 0.5f;
    v = sp ? 0.f : h;
    u64 bal = __ballot(sp);
    if (l == t) kvsm[((size_t)t * B_ + b) * 4 + j] = bal;
  }
}

// ---------- P3: attn = q & kvs -> sparse proj + bias + BN + identity ----------
__global__ __launch_bounds__(256) void proj_sparse(
    const u64* __restrict__ qm, const u64* __restrict__ kvsm,
    const float* __restrict__ wtp, const float* __restrict__ bnt,
    const float* __restrict__ pbias, const float* __restrict__ x,
    float* __restrict__ out) {
  int tb = blockIdx.x >> 5;
  int n0 = (blockIdx.x & 31) << 5;
  int t = tb >> 4, b = tb & 15;
  int tid = threadIdx.x;
  int l = tid & 63, w = tid >> 6;
  __shared__ float tile[C_ * 33];
  u64 kvm[4];
#pragma unroll
  for (int j = 0; j < 4; j++) kvm[j] = kvsm[((size_t)t * B_ + b) * 4 + j];
  for (int nn = w; nn < 32; nn += 4) {
    int n = n0 + nn;
    float acc[4] = {0.f, 0.f, 0.f, 0.f};
    size_t site = ((size_t)t * B_ + b) * N_ + n;
    const u64* mp = qm + (site << 2);
#pragma unroll
    for (int j = 0; j < 4; j++) {
      u64 m = mp[j] & kvm[j];
      while (m) {
        int li = __builtin_ctzll(m);
        m &= m - 1;
        int c = (li << 2) + j;
        const float* rp = wtp + c * C_;
#pragma unroll
        for (int jj = 0; jj < 4; jj++) acc[jj] += rp[(jj << 6) + l];
      }
    }
#pragma unroll
    for (int jj = 0; jj < 4; jj++) tile[((jj << 6) + l) * 33 + nn] = acc[jj];
  }
  __syncthreads();
  int col = l & 31;
  int half = l >> 5;
  for (int r = (w << 1) + half; r < C_; r += 8) {
    float val = tile[r * 33 + col];
    float z = (val + pbias[r]) * bnt[6 * C_ + r] + bnt[7 * C_ + r];
    size_t xi = (((size_t)t * B_ + b) * C_ + r) * N_ + n0 + col;
    out[xi] = z + x[xi];
  }
}

// ---------- diagnostic: if ws too small, zero the output ----------
__global__ __launch_bounds__(256) void fill_zero_f32(float* p, size_t n) {
  size_t i = (size_t)blockIdx.x * 256 + threadIdx.x;
  if (i < n) p[i] = 0.0f;
}

extern "C" void kernel_launch(void* const* d_in, const int* in_sizes, int n_in,
                              void* d_out, int out_size, void* d_ws, size_t ws_size,
                              hipStream_t stream) {
  const float* x  = (const float*)d_in[0];
  const float* qw = (const float*)d_in[1];
  const float* qg = (const float*)d_in[2];
  const float* qb = (const float*)d_in[3];
  const float* qm = (const float*)d_in[4];
  const float* qv = (const float*)d_in[5];
  const float* kw = (const float*)d_in[6];
  const float* kg = (const float*)d_in[7];
  const float* kb = (const float*)d_in[8];
  const float* km = (const float*)d_in[9];
  const float* kv = (const float*)d_in[10];
  const float* vw = (const float*)d_in[11];
  const float* vg = (const float*)d_in[12];
  const float* vb2 = (const float*)d_in[13];
  const float* vm = (const float*)d_in[14];
  const float* vv = (const float*)d_in[15];
  const float* pw = (const float*)d_in[16];
  const float* pbias = (const float*)d_in[17];
  const float* pg = (const float*)d_in[18];
  const float* pb = (const float*)d_in[19];
  const float* pm = (const float*)d_in[20];
  const float* pv = (const float*)d_in[21];

  const size_t needed = 8534016ull;
  if (ws_size < needed) {
    size_t n = (size_t)out_size;
    fill_zero_f32<<<(unsigned)((n + 255) / 256), 256, 0, stream>>>(
        (float*)d_out, n);
    return;
  }

  char* ws = (char*)d_ws;
  float* wqkv  = (float*)(ws + 0);         // 790 KB  [257][768], row 256 = 0
  float* wtp   = (float*)(ws + 790528);    // 256 KB  [c][o]
  float* bnt   = (float*)(ws + 1052672);   // 8 KB
  u64*   xsm   = (u64*)  (ws + 1060864);   // 2 MB   [site][4 words], c=64w+l
  u8*    lists = (u8*)   (ws + 3158016);   // 2 MB   [site][32] channel lists
  u16*   cnts  = (u16*)  (ws + 5255168);   // 128 KB [site]
  u64*   qmm   = (u64*)  (ws + 5386240);   // 2 MB   [site][4 j-words], c=4l+j
  u8*    pkvb  = (u8*)   (ws + 7483392);   // 1 MB   [t][b][c][64 tiles]
  u64*   kvsm  = (u64*)  (ws + 8531968);   // 2 KB   [t][b][4 j-words]

  float* out  = (float*)d_out;
  float* vout = out + (size_t)T_ * B_ * C_ * N_;

  prep_kernel<<<258, 256, 0, stream>>>(qw, kw, vw, pw,
                                       qg, qb, qm, qv, kg, kb, km, kv,
                                       vg, vb2, vm, vv, pg, pb, pm, pv,
                                       wqkv, wtp, bnt);
  lif_pack<<<512, 256, 0, stream>>>(x, xsm, lists, cnts);
  qkv_sparse<<<1024, 256, 0, stream>>>(xsm, lists, cnts, wqkv, bnt,
                                       pkvb, qmm, vout);
  kv_lif_kernel<<<16, 256, 0, stream>>>(pkvb, kvsm);
  proj_sparse<<<2048, 256, 0, stream>>>(qmm, kvsm, wtp, bnt, pbias, x, out);
}

// Round 9
// 146.948 us; speedup vs baseline: 1.0870x; 1.0870x over previous
//
#include <hip/hip_runtime.h>
#include <hip/hip_bf16.h>
#include <stdint.h>

#define T_ 4
#define B_ 16
#define C_ 256
#define N_ 1024
#define HEADS_ 8
#define HD_ 32

typedef unsigned long long u64;
typedef unsigned char u8;

// ---------- prep: transpose the 4 weight matrices to [c][o] ----------
__global__ __launch_bounds__(256) void prep_transpose(
    const float* __restrict__ qw, const float* __restrict__ kw,
    const float* __restrict__ vw, const float* __restrict__ pw,
    float* __restrict__ wtq, float* __restrict__ wtk,
    float* __restrict__ wtv, float* __restrict__ wtp) {
  int c = blockIdx.x;
  int o = threadIdx.x;
  wtq[c * C_ + o] = qw[o * C_ + c];
  wtk[c * C_ + o] = kw[o * C_ + c];
  wtv[c * C_ + o] = vw[o * C_ + c];
  wtp[c * C_ + o] = pw[o * C_ + c];
}

// ---------- prep: BN scale/shift tables (verified) ----------
__global__ __launch_bounds__(256) void prep_bn(
    const float* __restrict__ qg, const float* __restrict__ qb2,
    const float* __restrict__ qmn, const float* __restrict__ qvr,
    const float* __restrict__ kg, const float* __restrict__ kb2,
    const float* __restrict__ kmn, const float* __restrict__ kvr,
    const float* __restrict__ vg, const float* __restrict__ vb2,
    const float* __restrict__ vmn, const float* __restrict__ vvr,
    const float* __restrict__ pg, const float* __restrict__ pb2,
    const float* __restrict__ pmn, const float* __restrict__ pvr,
    float* __restrict__ bnt) {
  int c = threadIdx.x;
  float rs;
  rs = sqrtf(qvr[c] + 1e-5f);
  bnt[0 * C_ + c] = qg[c] / rs;
  bnt[1 * C_ + c] = qb2[c] - qmn[c] * qg[c] / rs;
  rs = sqrtf(kvr[c] + 1e-5f);
  bnt[2 * C_ + c] = kg[c] / rs;
  bnt[3 * C_ + c] = kb2[c] - kmn[c] * kg[c] / rs;
  rs = sqrtf(vvr[c] + 1e-5f);
  bnt[4 * C_ + c] = vg[c] / rs;
  bnt[5 * C_ + c] = vb2[c] - vmn[c] * vg[c] / rs;
  rs = sqrtf(pvr[c] + 1e-5f);
  bnt[6 * C_ + c] = pg[c] / rs;
  bnt[7 * C_ + c] = pb2[c] - pmn[c] * pg[c] / rs;
}

// ---------- P0: shortcut LIF -> xs bitmasks [site][4 words], c = 64w + l ----
__global__ __launch_bounds__(256) void lif_shortcut(const float* __restrict__ x,
                                                    u64* __restrict__ xsm) {
  int b = blockIdx.x >> 5;          // 32 n-tiles of 32
  int n0 = (blockIdx.x & 31) << 5;
  int tid = threadIdx.x;
  int l = tid & 63, w = tid >> 6;
  __shared__ float tile[C_ * 33];
  float v[32];
#pragma unroll
  for (int i = 0; i < 32; i++) v[i] = 0.f;
  int c = (w << 6) + l;             // this thread's channel
  for (int t = 0; t < T_; t++) {
    __syncthreads();
    const float* xp = x + (((size_t)t * B_ + b) * C_) * N_ + n0;
    for (int idx = tid; idx < C_ * 32; idx += 256) {
      int cc = idx >> 5, nn = idx & 31;
      tile[cc * 33 + nn] = xp[(size_t)cc * N_ + nn];
    }
    __syncthreads();
#pragma unroll
    for (int nn = 0; nn < 32; nn++) {
      float xv = tile[c * 33 + nn];
      float h = v[nn] + (xv - v[nn]) * 0.5f;   // tau=2 exact halving
      bool s = h >= 1.0f;
      v[nn] = s ? 0.f : h;                     // hard reset, detach
      u64 bal = __ballot(s);
      if (l == nn) xsm[(((size_t)t * B_ + b) * N_ + n0 + nn) * 4 + w] = bal;
    }
  }
}

// ---------- P1: sparse q/k/v conv + BN + LIF (r5 structure, 8 sites/block) --
// grid = b(16) x nt(128 tiles of 8 n); wave wv owns sites nn = wv, wv+4.
// lane l owns out-channels o = 64j + l, j=0..3.
__global__ __launch_bounds__(256) void qkv_sparse(
    const u64* __restrict__ xsm,
    const float* __restrict__ wtq, const float* __restrict__ wtk,
    const float* __restrict__ wtv, const float* __restrict__ bnt,
    float* __restrict__ pkv, u64* __restrict__ qm_out,
    float* __restrict__ vout) {
  int b = blockIdx.x >> 7;
  int nt = blockIdx.x & 127;
  int n0 = nt << 3;
  int tid = threadIdx.x;
  int l = tid & 63, wv = tid >> 6;
  float qs[4], qsh[4], ks[4], ksh[4], vsc[4], vsh[4];
#pragma unroll
  for (int j = 0; j < 4; j++) {
    int o = (j << 6) + l;
    qs[j]  = bnt[0 * C_ + o]; qsh[j] = bnt[1 * C_ + o];
    ks[j]  = bnt[2 * C_ + o]; ksh[j] = bnt[3 * C_ + o];
    vsc[j] = bnt[4 * C_ + o]; vsh[j] = bnt[5 * C_ + o];
  }
  int cnt[4][4];
#pragma unroll
  for (int t = 0; t < 4; t++)
#pragma unroll
    for (int j = 0; j < 4; j++) cnt[t][j] = 0;

  for (int nn = wv; nn < 8; nn += 4) {
    int n = n0 + nn;
    float aq[4][4], ak[4][4], av[4][4];   // [t][j]
#pragma unroll
    for (int t = 0; t < 4; t++)
#pragma unroll
      for (int j = 0; j < 4; j++) { aq[t][j] = 0.f; ak[t][j] = 0.f; av[t][j] = 0.f; }
#pragma unroll
    for (int t = 0; t < 4; t++) {
      const u64* mp = xsm + ((((size_t)t * B_ + b) * N_ + n) << 2);
#pragma unroll
      for (int wd = 0; wd < 4; wd++) {
        u64 m = mp[wd];                    // wave-uniform, register walk
        while (m) {
          int c = (wd << 6) + __builtin_ctzll(m);
          m &= (m - 1);
          const float* rq = wtq + c * C_;
          const float* rk = wtk + c * C_;
          const float* rv = wtv + c * C_;
#pragma unroll
          for (int j = 0; j < 4; j++) {
            int o = (j << 6) + l;
            aq[t][j] += rq[o];
            ak[t][j] += rk[o];
            av[t][j] += rv[o];
          }
        }
      }
    }
    // BN + LIF scan over t (verified math)
#pragma unroll
    for (int j = 0; j < 4; j++) {
      int o = (j << 6) + l;
      float vq = 0.f, vk = 0.f, vv = 0.f;
#pragma unroll
      for (int t = 0; t < 4; t++) {
        float pq = aq[t][j] * qs[j] + qsh[j];
        float pk = ak[t][j] * ks[j] + ksh[j];
        float pv = av[t][j] * vsc[j] + vsh[j];
        float hq = vq + (pq - vq) * 0.5f;
        float hk = vk + (pk - vk) * 0.5f;
        float hv = vv + (pv - vv) * 0.5f;
        bool sq = hq >= 1.0f; vq = sq ? 0.f : hq;
        bool sk = hk >= 1.0f; vk = sk ? 0.f : hk;
        bool sv = hv >= 1.0f; vv = sv ? 0.f : hv;
        cnt[t][j] += (sk && sv) ? 1 : 0;
        vout[(((size_t)t * B_ + b) * HEADS_ + (o >> 5)) * ((size_t)N_ * HD_) +
             (size_t)n * HD_ + (o & 31)] = sv ? 1.0f : 0.0f;
        u64 bal = __ballot(sq);
        if (l == (t << 2) + j)
          qm_out[((((size_t)t * B_ + b) * N_ + n) << 2) + j] = bal;
      }
    }
  }
  // cross-wave reduction of kv partial counts (deterministic, no atomics)
  __shared__ int scnt[4][4][C_];
#pragma unroll
  for (int t = 0; t < 4; t++)
#pragma unroll
    for (int j = 0; j < 4; j++) scnt[wv][t][(j << 6) + l] = cnt[t][j];
  __syncthreads();
  // coalesced pkv write: layout [t][b][nt][c] -> 1 KB contiguous per t
  for (int idx = tid; idx < 4 * C_; idx += 256) {
    int t = idx >> 8, c = idx & 255;
    int s = scnt[0][t][c] + scnt[1][t][c] + scnt[2][t][c] + scnt[3][t][c];
    pkv[(((size_t)t * B_ + b) * 128 + nt) * C_ + c] = (float)s;
  }
}

// ---------- P2: reduce kv partials + talking-heads LIF (v_th=0.5) ----------
// thread c; wave j = c>>6, lane l = c&63; ballot word j, bit l <-> c = 64j+l.
__global__ __launch_bounds__(256) void kv_lif_kernel(const float* __restrict__ pkv,
                                                     u64* __restrict__ kvsm) {
  int b = blockIdx.x;
  int c = threadIdx.x;
  int l = c & 63, j = c >> 6;
  float v = 0.f;
  for (int t = 0; t < 4; t++) {
    const float* p = pkv + (((size_t)t * B_ + b) * 128) * C_ + c;
    float kv = 0.f;
#pragma unroll
    for (int i = 0; i < 128; i++) kv += p[(size_t)i * C_];  // exact ints
    float h = v + (kv - v) * 0.5f;
    bool s = h >= 0.5f;
    v = s ? 0.f : h;
    u64 bal = __ballot(s);
    if (l == t) kvsm[((size_t)t * B_ + b) * 4 + j] = bal;
  }
}

// ---------- P3: attn = q & kvs -> sparse proj + bias + BN + identity ----------
__global__ __launch_bounds__(256) void proj_sparse(
    const u64* __restrict__ qm, const u64* __restrict__ kvsm,
    const float* __restrict__ wtp, const float* __restrict__ bnt,
    const float* __restrict__ pbias, const float* __restrict__ x,
    float* __restrict__ out) {
  int tb = blockIdx.x >> 5;         // 64 (t,b) x 32 n-tiles of 32
  int n0 = (blockIdx.x & 31) << 5;
  int t = tb >> 4, b = tb & 15;
  int tid = threadIdx.x;
  int l = tid & 63, w = tid >> 6;
  __shared__ float tile[C_ * 33];
  u64 kvm[4];
#pragma unroll
  for (int wd = 0; wd < 4; wd++) kvm[wd] = kvsm[((size_t)t * B_ + b) * 4 + wd];
  for (int nn = w; nn < 32; nn += 4) {
    int n = n0 + nn;
    float acc[4] = {0.f, 0.f, 0.f, 0.f};
    const u64* mp = qm + ((((size_t)t * B_ + b) * N_ + n) << 2);
#pragma unroll
    for (int wd = 0; wd < 4; wd++) {
      u64 m = mp[wd] & kvm[wd];
      while (m) {
        int c = (wd << 6) + __builtin_ctzll(m);
        m &= (m - 1);
        const float* rp = wtp + c * C_;
#pragma unroll
        for (int j = 0; j < 4; j++) acc[j] += rp[(j << 6) + l];
      }
    }
#pragma unroll
    for (int j = 0; j < 4; j++) tile[((j << 6) + l) * 33 + nn] = acc[j];
  }
  __syncthreads();
  // per-row epilogue, coalesced over n (verified math)
  int col = l & 31;
  int half = l >> 5;
  for (int r = (w << 1) + half; r < C_; r += 8) {
    float val = tile[r * 33 + col];
    float z = (val + pbias[r]) * bnt[6 * C_ + r] + bnt[7 * C_ + r];
    size_t xi = (((size_t)t * B_ + b) * C_ + r) * N_ + n0 + col;
    out[xi] = z + x[xi];
  }
}

// ---------- diagnostic: if ws too small, zero the output ----------
__global__ __launch_bounds__(256) void fill_zero_f32(float* p, size_t n) {
  size_t i = (size_t)blockIdx.x * 256 + threadIdx.x;
  if (i < n) p[i] = 0.0f;
}

extern "C" void kernel_launch(void* const* d_in, const int* in_sizes, int n_in,
                              void* d_out, int out_size, void* d_ws, size_t ws_size,
                              hipStream_t stream) {
  const float* x  = (const float*)d_in[0];
  const float* qw = (const float*)d_in[1];
  const float* qg = (const float*)d_in[2];
  const float* qb = (const float*)d_in[3];
  const float* qm = (const float*)d_in[4];
  const float* qv = (const float*)d_in[5];
  const float* kw = (const float*)d_in[6];
  const float* kg = (const float*)d_in[7];
  const float* kb = (const float*)d_in[8];
  const float* km = (const float*)d_in[9];
  const float* kv = (const float*)d_in[10];
  const float* vw = (const float*)d_in[11];
  const float* vg = (const float*)d_in[12];
  const float* vb2 = (const float*)d_in[13];
  const float* vm = (const float*)d_in[14];
  const float* vv = (const float*)d_in[15];
  const float* pw = (const float*)d_in[16];
  const float* pbias = (const float*)d_in[17];
  const float* pg = (const float*)d_in[18];
  const float* pb = (const float*)d_in[19];
  const float* pm = (const float*)d_in[20];
  const float* pv = (const float*)d_in[21];

  const size_t needed = 13641728ull;   // ~13.6 MB (ws proven >= 43 MB in r2)
  if (ws_size < needed) {
    size_t n = (size_t)out_size;
    fill_zero_f32<<<(unsigned)((n + 255) / 256), 256, 0, stream>>>(
        (float*)d_out, n);
    return;
  }

  char* ws = (char*)d_ws;
  float* wtq = (float*)(ws + 0);         // 256 KB [c][o]
  float* wtk = (float*)(ws + 262144);    // 256 KB
  float* wtv = (float*)(ws + 524288);    // 256 KB
  float* wtp = (float*)(ws + 786432);    // 256 KB
  float* bnt = (float*)(ws + 1048576);   // 8 KB
  u64*   xsm = (u64*)  (ws + 1056768);   // 2 MB  [site][4 words], c = 64w+l
  u64*   qmm = (u64*)  (ws + 3153920);   // 2 MB  [site][4 words], c = 64j+l
  float* pkv = (float*)(ws + 5251072);   // 8 MB  [t][b][nt(128)][c]
  u64*   kvsm = (u64*) (ws + 13639680);  // 2 KB  [t][b][4 words]

  float* out  = (float*)d_out;
  float* vout = out + (size_t)T_ * B_ * C_ * N_;

  prep_transpose<<<256, 256, 0, stream>>>(qw, kw, vw, pw, wtq, wtk, wtv, wtp);
  prep_bn<<<1, 256, 0, stream>>>(qg, qb, qm, qv, kg, kb, km, kv,
                                 vg, vb2, vm, vv, pg, pb, pm, pv, bnt);
  lif_shortcut<<<512, 256, 0, stream>>>(x, xsm);
  qkv_sparse<<<2048, 256, 0, stream>>>(xsm, wtq, wtk, wtv, bnt, pkv, qmm, vout);
  kv_lif_kernel<<<16, 256, 0, stream>>>(pkv, kvsm);
  proj_sparse<<<2048, 256, 0, stream>>>(qmm, kvsm, wtp, bnt, pbias, x, out);
}